// Round 6
// baseline (254.135 us; speedup 1.0000x reference)
//
#include <hip/hip_runtime.h>

#define N_NODES 50000
#define N_EDGES 800000
#define D 64
#define NCHUNK 64
#define CHUNK_E (N_EDGES / NCHUNK)   // 12500 edges per chunk
#define NRANGE 4
#define RANGE_N 16384                // nodes per range (pow2); 4*16384 >= 50000
#define PAD 8
#define REC_CAP (N_EDGES + (PAD - 1) * N_NODES)   // 1,150,000 records
#define REC_F4 ((REC_CAP * 8) / 16)               // 575,000 float4s
#define XW_BLOCKS ((N_NODES + 127) / 128)         // 391
#define HIST_BLOCKS (NCHUNK * NRANGE)             // 256
#define ZERO_BLOCKS ((REC_F4 + 511) / 512)        // 1124
#define MEGA_BLOCKS (XW_BLOCKS + HIST_BLOCKS + ZERO_BLOCKS)

__device__ __forceinline__ unsigned short f2bf(float f) {   // RNE float->bf16
    unsigned int u = __float_as_uint(f);
    u += 0x7FFFu + ((u >> 16) & 1u);
    return (unsigned short)(u >> 16);
}
__device__ __forceinline__ float bf2f(unsigned short s) {
    return __uint_as_float((unsigned int)s << 16);
}

// ---------- mega: xw=x@W (bf16) | LDS histogram+lrank | zero rec ----------
__global__ __launch_bounds__(512) void k_mega(const float* __restrict__ x,
                                              const float* __restrict__ W,
                                              const int* __restrict__ col,
                                              unsigned short* __restrict__ part,
                                              unsigned short* __restrict__ lrank,
                                              unsigned short* __restrict__ xw16,
                                              float4* __restrict__ rec4) {
    __shared__ unsigned int smem[16384];   // 64 KiB union
    int b = blockIdx.x, t = threadIdx.x;
    if (b < XW_BLOCKS) {
        // ---- xw path: 128 rows/block, 4 rows x 4 cols per thread ----
        float* Ws = (float*)smem;          // 4096 floats
        float* xs = (float*)smem + 4096;   // 128*68 = 8704 floats (pad 68)
        int r0 = b * 128;
        for (int i = t; i < 1024; i += 512)
            ((float4*)Ws)[i] = ((const float4*)W)[i];
        for (int i = t; i < 2048; i += 512) {
            int row = i >> 4, k4 = i & 15;
            int gr = r0 + row;
            float4 v = make_float4(0.f, 0.f, 0.f, 0.f);
            if (gr < N_NODES) v = ((const float4*)x)[gr * 16 + k4];
            *(float4*)&xs[row * 68 + k4 * 4] = v;
        }
        __syncthreads();
        int cg = t & 15;      // 4-col group
        int rg = t >> 4;      // 0..31; rows rg + 32*i
        float4 acc[4];
#pragma unroll
        for (int i = 0; i < 4; ++i) acc[i] = make_float4(0.f, 0.f, 0.f, 0.f);
        for (int k4 = 0; k4 < 16; ++k4) {
            float4 xv[4];
#pragma unroll
            for (int i = 0; i < 4; ++i)
                xv[i] = *(const float4*)&xs[(rg + 32 * i) * 68 + k4 * 4];
            float4 w0 = *(const float4*)&Ws[(k4 * 4 + 0) * 64 + cg * 4];
            float4 w1 = *(const float4*)&Ws[(k4 * 4 + 1) * 64 + cg * 4];
            float4 w2 = *(const float4*)&Ws[(k4 * 4 + 2) * 64 + cg * 4];
            float4 w3 = *(const float4*)&Ws[(k4 * 4 + 3) * 64 + cg * 4];
#pragma unroll
            for (int i = 0; i < 4; ++i) {
                acc[i].x = fmaf(xv[i].x, w0.x, acc[i].x); acc[i].y = fmaf(xv[i].x, w0.y, acc[i].y);
                acc[i].z = fmaf(xv[i].x, w0.z, acc[i].z); acc[i].w = fmaf(xv[i].x, w0.w, acc[i].w);
                acc[i].x = fmaf(xv[i].y, w1.x, acc[i].x); acc[i].y = fmaf(xv[i].y, w1.y, acc[i].y);
                acc[i].z = fmaf(xv[i].y, w1.z, acc[i].z); acc[i].w = fmaf(xv[i].y, w1.w, acc[i].w);
                acc[i].x = fmaf(xv[i].z, w2.x, acc[i].x); acc[i].y = fmaf(xv[i].z, w2.y, acc[i].y);
                acc[i].z = fmaf(xv[i].z, w2.z, acc[i].z); acc[i].w = fmaf(xv[i].z, w2.w, acc[i].w);
                acc[i].x = fmaf(xv[i].w, w3.x, acc[i].x); acc[i].y = fmaf(xv[i].w, w3.y, acc[i].y);
                acc[i].z = fmaf(xv[i].w, w3.z, acc[i].z); acc[i].w = fmaf(xv[i].w, w3.w, acc[i].w);
            }
        }
#pragma unroll
        for (int i = 0; i < 4; ++i) {
            int row = r0 + rg + 32 * i;
            if (row < N_NODES) {
                ushort4 s4 = make_ushort4(f2bf(acc[i].x), f2bf(acc[i].y),
                                          f2bf(acc[i].z), f2bf(acc[i].w));
                *(ushort4*)&xw16[row * 64 + cg * 4] = s4;
            }
        }
    } else if (b < XW_BLOCKS + HIST_BLOCKS) {
        // ---- hist path: chunk i, range j ----
        unsigned int* h = smem;
        int hb = b - XW_BLOCKS;
        int i = hb >> 2;   // chunk 0..63
        int j = hb & 3;    // range 0..3
        for (int k = t; k < RANGE_N; k += 512) h[k] = 0;
        __syncthreads();
        int base = i * CHUNK_E;
        for (int e = base + t; e < base + CHUNK_E; e += 512) {
            int c = col[e];
            if ((c >> 14) == j)
                lrank[e] = (unsigned short)atomicAdd(&h[c & (RANGE_N - 1)], 1u);
        }
        __syncthreads();
        for (int k = t; k < RANGE_N; k += 512) {
            int n = j * RANGE_N + k;
            if (n < N_NODES) part[(size_t)i * N_NODES + n] = (unsigned short)h[k];
        }
    } else {
        // ---- zero rec path ----
        int idx = (b - XW_BLOCKS - HIST_BLOCKS) * 512 + t;
        if (idx < REC_F4) rec4[idx] = make_float4(0.f, 0.f, 0.f, 0.f);
    }
}

// ---------- per-node exclusive scan over chunk counts; PADDED total ----------
__global__ __launch_bounds__(256) void k_scanchunks(unsigned short* __restrict__ part,
                                                    int* __restrict__ cnttot) {
    int n = blockIdx.x * blockDim.x + threadIdx.x;
    if (n < N_NODES) {
        unsigned int run = 0;
#pragma unroll 8
        for (int i = 0; i < NCHUNK; ++i) {
            size_t idx = (size_t)i * N_NODES + n;
            unsigned int v = part[idx];
            part[idx] = (unsigned short)run;
            run += v;
        }
        cnttot[n] = (int)((run + PAD - 1) & ~(unsigned)(PAD - 1));
    }
}

// ---------- scan pass 1 over N+1 elements ----------
__global__ __launch_bounds__(256) void k_scan1(const int* __restrict__ cnt,
                                               int* __restrict__ start,
                                               int* __restrict__ partials) {
    __shared__ int s[512];
    int t = threadIdx.x, b = blockIdx.x;
    int i0 = b * 512 + t, i1 = i0 + 256;
    int v0 = (i0 < N_NODES) ? cnt[i0] : 0;
    int v1 = (i1 < N_NODES) ? cnt[i1] : 0;
    s[t] = v0; s[t + 256] = v1;
    __syncthreads();
    for (int off = 1; off < 512; off <<= 1) {
        int a0 = (t >= off) ? s[t - off] : 0;
        int a1 = s[t + 256 - off];
        __syncthreads();
        s[t] += a0; s[t + 256] += a1;
        __syncthreads();
    }
    if (i0 <= N_NODES) start[i0] = s[t] - v0;
    if (i1 <= N_NODES) start[i1] = s[t + 256] - v1;
    if (t == 255) partials[b] = s[511];
}

__global__ __launch_bounds__(128) void k_scan2(int* __restrict__ partials, int nblk) {
    __shared__ int s[128];
    int t = threadIdx.x;
    int v = (t < nblk) ? partials[t] : 0;
    s[t] = v;
    __syncthreads();
    for (int off = 1; off < 128; off <<= 1) {
        int a = (t >= off) ? s[t - off] : 0;
        __syncthreads();
        s[t] += a;
        __syncthreads();
    }
    if (t < nblk) partials[t] = s[t] - v;
}

__global__ __launch_bounds__(256) void k_scan3(int* __restrict__ start,
                                               const int* __restrict__ partials) {
    int t = threadIdx.x, b = blockIdx.x;
    int add = partials[b];
    int i0 = b * 512 + t, i1 = i0 + 256;
    if (i0 <= N_NODES) start[i0] += add;
    if (i1 <= N_NODES) start[i1] += add;
}

// ---------- place records (src, ew) at deterministic positions ----------
__global__ __launch_bounds__(256) void k_place(const int* __restrict__ ei,
                                               const float* __restrict__ ew,
                                               const int* __restrict__ start,
                                               const unsigned short* __restrict__ part,
                                               const unsigned short* __restrict__ lrank,
                                               int2* __restrict__ rec) {
    int e = blockIdx.x * blockDim.x + threadIdx.x;
    if (e < N_EDGES) {
        int c = ei[N_EDGES + e];
        int i = e / CHUNK_E;
        int pos = start[c] + (int)part[(size_t)i * N_NODES + c] + (int)lrank[e];
        rec[pos] = make_int2(ei[e], __float_as_int(ew[e]));
    }
}

// ---------- deg from CSR: dis = rsqrt(1 + sum ew); pads add 0 ----------
__global__ __launch_bounds__(256) void k_deg(const int* __restrict__ start,
                                             const int2* __restrict__ rec,
                                             float* __restrict__ dis) {
    int n = blockIdx.x * blockDim.x + threadIdx.x;
    if (n < N_NODES) {
        float s = 1.0f;   // self-loop weight
        int j1 = start[n + 1];
        for (int j = start[n]; j < j1; ++j) s += __int_as_float(rec[j].y);
        dis[n] = rsqrtf(s);
    }
}

// ---------- gather: one wave per node, unroll-8, bf16 rows ----------
__global__ __launch_bounds__(256) void k_gather(const int* __restrict__ start,
                                                const int2* __restrict__ rec,
                                                const unsigned short* __restrict__ xw16,
                                                const float* __restrict__ dis,
                                                const float* __restrict__ bias,
                                                float* __restrict__ out) {
    int wave = threadIdx.x >> 6;
    int c = threadIdx.x & 63;
    int n = blockIdx.x * 4 + wave;   // 12500 * 4 = 50000 exact
    float di = dis[n];
    float acc0 = di * bf2f(xw16[n * 64 + c]);   // self-loop: dis[n]^2 * xw[n] (outer di later)
    float acc1 = 0.f, acc2 = 0.f, acc3 = 0.f, acc4 = 0.f, acc5 = 0.f, acc6 = 0.f, acc7 = 0.f;
    int j = start[n], jend = start[n + 1];      // multiple of 8 (zero-padded)
    for (; j < jend; j += 8) {
        int2 r0 = rec[j + 0], r1 = rec[j + 1], r2 = rec[j + 2], r3 = rec[j + 3];
        int2 r4 = rec[j + 4], r5 = rec[j + 5], r6 = rec[j + 6], r7 = rec[j + 7];
        float w0 = dis[r0.x] * __int_as_float(r0.y);
        float w1 = dis[r1.x] * __int_as_float(r1.y);
        float w2 = dis[r2.x] * __int_as_float(r2.y);
        float w3 = dis[r3.x] * __int_as_float(r3.y);
        float w4 = dis[r4.x] * __int_as_float(r4.y);
        float w5 = dis[r5.x] * __int_as_float(r5.y);
        float w6 = dis[r6.x] * __int_as_float(r6.y);
        float w7 = dis[r7.x] * __int_as_float(r7.y);
        float v0 = bf2f(xw16[r0.x * 64 + c]), v1 = bf2f(xw16[r1.x * 64 + c]);
        float v2 = bf2f(xw16[r2.x * 64 + c]), v3 = bf2f(xw16[r3.x * 64 + c]);
        float v4 = bf2f(xw16[r4.x * 64 + c]), v5 = bf2f(xw16[r5.x * 64 + c]);
        float v6 = bf2f(xw16[r6.x * 64 + c]), v7 = bf2f(xw16[r7.x * 64 + c]);
        acc0 = fmaf(v0, w0, acc0);
        acc1 = fmaf(v1, w1, acc1);
        acc2 = fmaf(v2, w2, acc2);
        acc3 = fmaf(v3, w3, acc3);
        acc4 = fmaf(v4, w4, acc4);
        acc5 = fmaf(v5, w5, acc5);
        acc6 = fmaf(v6, w6, acc6);
        acc7 = fmaf(v7, w7, acc7);
    }
    float acc = ((acc0 + acc1) + (acc2 + acc3)) + ((acc4 + acc5) + (acc6 + acc7));
    out[n * 64 + c] = fmaf(acc, di, bias[c]);
}

extern "C" void kernel_launch(void* const* d_in, const int* in_sizes, int n_in,
                              void* d_out, int out_size, void* d_ws, size_t ws_size,
                              hipStream_t stream) {
    const float* x    = (const float*)d_in[0];
    const float* W    = (const float*)d_in[1];
    const float* bias = (const float*)d_in[2];
    const float* ew   = (const float*)d_in[3];
    const int*   ei   = (const int*)d_in[4];   // (2,E) flat: [0:E) src, [E:2E) dst
    float* out = (float*)d_out;

    // ---- workspace layout (bytes; ws is ~256 MB, all regions disjoint) ----
    char* wsb = (char*)d_ws;
    int2*           rec   = (int2*)wsb;                              //  9,200,000 B
    unsigned short* xw16  = (unsigned short*)(wsb + 9200000);        //  6,400,000 B
    unsigned short* lrank = (unsigned short*)(wsb + 15600000);       //  1,600,000 B
    unsigned short* part  = (unsigned short*)(wsb + 17200000);       //  6,400,000 B
    float*          dis   = (float*)(wsb + 23600000);                //    200,000 B
    int*            cnttot= (int*)(wsb + 23800000);                  //    200,000 B
    int*            start = (int*)(wsb + 24000000);                  //    200,004 B
    int*            partials = (int*)(wsb + 24200016);

    const int NB_SCAN = (N_NODES + 1 + 511) / 512;   // 98
    const int NB_NODE = (N_NODES + 255) / 256;       // 196

    k_mega<<<MEGA_BLOCKS, 512, 0, stream>>>(x, W, ei + N_EDGES, part, lrank, xw16, (float4*)rec);
    k_scanchunks<<<NB_NODE, 256, 0, stream>>>(part, cnttot);
    k_scan1<<<NB_SCAN, 256, 0, stream>>>(cnttot, start, partials);
    k_scan2<<<1, 128, 0, stream>>>(partials, NB_SCAN);
    k_scan3<<<NB_SCAN, 256, 0, stream>>>(start, partials);
    k_place<<<N_EDGES / 256, 256, 0, stream>>>(ei, ew, start, part, lrank, rec);
    k_deg<<<NB_NODE, 256, 0, stream>>>(start, rec, dis);
    k_gather<<<N_NODES / 4, 256, 0, stream>>>(start, rec, xw16, dis, bias, out);
}

// Round 7
// 109.153 us; speedup vs baseline: 2.3282x; 2.3282x over previous
//
#include <hip/hip_runtime.h>

#define N_NODES 50000
#define N_EDGES 800000
#define D 64
#define NCHUNK 64
#define CHUNK_E (N_EDGES / NCHUNK)   // 12500 edges per chunk
#define NRANGE 8
#define RANGE_N 8192                 // nodes per range (pow2); 8*8192 >= 50000
#define PAD 8                        // bucket padding -> pure unroll-8 gather
#define REC_CAP (N_EDGES + (PAD - 1) * N_NODES)   // 1,150,000 records max

__device__ __forceinline__ unsigned short f2bf(float f) {   // RNE float->bf16
    unsigned int u = __float_as_uint(f);
    u += 0x7FFFu + ((u >> 16) & 1u);
    return (unsigned short)(u >> 16);
}
__device__ __forceinline__ float bf2f(unsigned short s) {
    return __uint_as_float((unsigned int)s << 16);
}

// ---------- LDS histogram + local ranks (no global atomics) ----------
__global__ __launch_bounds__(256) void k_hist(const int* __restrict__ col,
                                              unsigned short* __restrict__ part,
                                              unsigned short* __restrict__ lrank) {
    __shared__ unsigned int h[RANGE_N];   // 32 KiB
    int i = blockIdx.x >> 3;   // chunk 0..63
    int j = blockIdx.x & 7;    // range 0..7
    int t = threadIdx.x;
    for (int k = t; k < RANGE_N; k += 256) h[k] = 0;
    __syncthreads();
    int base = i * CHUNK_E;
    for (int e = base + t; e < base + CHUNK_E; e += 256) {
        int c = col[e];
        if ((c >> 13) == j) {
            unsigned int lr = atomicAdd(&h[c & (RANGE_N - 1)], 1u);
            lrank[e] = (unsigned short)lr;
        }
    }
    __syncthreads();
    for (int k = t; k < RANGE_N; k += 256) {
        int n = j * RANGE_N + k;
        if (n < N_NODES) part[(size_t)i * N_NODES + n] = (unsigned short)h[k];
    }
}

// ---------- per-node exclusive scan over chunk counts; output PADDED total ----------
__global__ __launch_bounds__(256) void k_scanchunks(unsigned short* __restrict__ part,
                                                    int* __restrict__ cnttot) {
    int n = blockIdx.x * blockDim.x + threadIdx.x;
    if (n < N_NODES) {
        unsigned int run = 0;
#pragma unroll 8
        for (int i = 0; i < NCHUNK; ++i) {
            size_t idx = (size_t)i * N_NODES + n;
            unsigned int v = part[idx];
            part[idx] = (unsigned short)run;
            run += v;
        }
        cnttot[n] = (int)((run + PAD - 1) & ~(unsigned)(PAD - 1));
    }
}

// ---------- scan pass 1 over N+1 elements ----------
__global__ __launch_bounds__(256) void k_scan1(const int* __restrict__ cnt,
                                               int* __restrict__ start,
                                               int* __restrict__ partials) {
    __shared__ int s[512];
    int t = threadIdx.x, b = blockIdx.x;
    int i0 = b * 512 + t, i1 = i0 + 256;
    int v0 = (i0 < N_NODES) ? cnt[i0] : 0;
    int v1 = (i1 < N_NODES) ? cnt[i1] : 0;
    s[t] = v0; s[t + 256] = v1;
    __syncthreads();
    for (int off = 1; off < 512; off <<= 1) {
        int a0 = (t >= off) ? s[t - off] : 0;
        int a1 = s[t + 256 - off];
        __syncthreads();
        s[t] += a0; s[t + 256] += a1;
        __syncthreads();
    }
    if (i0 <= N_NODES) start[i0] = s[t] - v0;
    if (i1 <= N_NODES) start[i1] = s[t + 256] - v1;
    if (t == 255) partials[b] = s[511];
}

__global__ __launch_bounds__(128) void k_scan2(int* __restrict__ partials, int nblk) {
    __shared__ int s[128];
    int t = threadIdx.x;
    int v = (t < nblk) ? partials[t] : 0;
    s[t] = v;
    __syncthreads();
    for (int off = 1; off < 128; off <<= 1) {
        int a = (t >= off) ? s[t - off] : 0;
        __syncthreads();
        s[t] += a;
        __syncthreads();
    }
    if (t < nblk) partials[t] = s[t] - v;
}

__global__ __launch_bounds__(256) void k_scan3(int* __restrict__ start,
                                               const int* __restrict__ partials) {
    int t = threadIdx.x, b = blockIdx.x;
    int add = partials[b];
    int i0 = b * 512 + t, i1 = i0 + 256;
    if (i0 <= N_NODES) start[i0] += add;
    if (i1 <= N_NODES) start[i1] += add;
}

// ---------- zero rec (pad slots must be (0, 0.0f)) ----------
__global__ __launch_bounds__(256) void k_zero_rec(float4* __restrict__ rec4) {
    int i = blockIdx.x * blockDim.x + threadIdx.x;
    if (i < (REC_CAP * 8) / 16) rec4[i] = make_float4(0.f, 0.f, 0.f, 0.f);
}

// ---------- place records (src, ew) at deterministic positions ----------
__global__ __launch_bounds__(256) void k_place(const int* __restrict__ ei,
                                               const float* __restrict__ ew,
                                               const int* __restrict__ start,
                                               const unsigned short* __restrict__ part,
                                               const unsigned short* __restrict__ lrank,
                                               int2* __restrict__ rec) {
    int e = blockIdx.x * blockDim.x + threadIdx.x;
    if (e < N_EDGES) {
        int c = ei[N_EDGES + e];
        int i = e / CHUNK_E;
        int pos = start[c] + (int)part[(size_t)i * N_NODES + c] + (int)lrank[e];
        rec[pos] = make_int2(ei[e], __float_as_int(ew[e]));
    }
}

// ---------- deg from CSR: dis = rsqrt(1 + sum ew over bucket); pads add 0 ----------
__global__ __launch_bounds__(256) void k_deg(const int* __restrict__ start,
                                             const int2* __restrict__ rec,
                                             float* __restrict__ dis) {
    int n = blockIdx.x * blockDim.x + threadIdx.x;
    if (n < N_NODES) {
        float s = 1.0f;   // self-loop weight
        int j1 = start[n + 1];
        for (int j = start[n]; j < j1; ++j) s += __int_as_float(rec[j].y);
        dis[n] = rsqrtf(s);
    }
}

// ---------- xw16 = bf16( dis[row] * (x @ W) )  (pre-scaled rows) ----------
__global__ __launch_bounds__(256) void k_xw(const float* __restrict__ x,
                                            const float* __restrict__ W,
                                            const float* __restrict__ dis,
                                            unsigned short* __restrict__ xw16) {
    __shared__ float Ws[64 * 64];
    __shared__ float xs[128 * 68];
    int t = threadIdx.x;
    int r0 = blockIdx.x * 128;

    for (int i = t; i < 1024; i += 256)
        ((float4*)Ws)[i] = ((const float4*)W)[i];
    for (int i = t; i < 2048; i += 256) {
        int row = i >> 4, k4 = i & 15;
        int gr = r0 + row;
        float4 v = make_float4(0.f, 0.f, 0.f, 0.f);
        if (gr < N_NODES) v = ((const float4*)x)[gr * 16 + k4];
        *(float4*)&xs[row * 68 + k4 * 4] = v;
    }
    __syncthreads();

    int cg = t & 15;
    int rg = t >> 4;
    float4 acc[8];
#pragma unroll
    for (int i = 0; i < 8; ++i) acc[i] = make_float4(0.f, 0.f, 0.f, 0.f);

    for (int k4 = 0; k4 < 16; ++k4) {
        float4 xv[8];
#pragma unroll
        for (int i = 0; i < 8; ++i)
            xv[i] = *(const float4*)&xs[(rg + 16 * i) * 68 + k4 * 4];
        float4 w0 = *(const float4*)&Ws[(k4 * 4 + 0) * 64 + cg * 4];
        float4 w1 = *(const float4*)&Ws[(k4 * 4 + 1) * 64 + cg * 4];
        float4 w2 = *(const float4*)&Ws[(k4 * 4 + 2) * 64 + cg * 4];
        float4 w3 = *(const float4*)&Ws[(k4 * 4 + 3) * 64 + cg * 4];
#pragma unroll
        for (int i = 0; i < 8; ++i) {
            acc[i].x = fmaf(xv[i].x, w0.x, acc[i].x); acc[i].y = fmaf(xv[i].x, w0.y, acc[i].y);
            acc[i].z = fmaf(xv[i].x, w0.z, acc[i].z); acc[i].w = fmaf(xv[i].x, w0.w, acc[i].w);
            acc[i].x = fmaf(xv[i].y, w1.x, acc[i].x); acc[i].y = fmaf(xv[i].y, w1.y, acc[i].y);
            acc[i].z = fmaf(xv[i].y, w1.z, acc[i].z); acc[i].w = fmaf(xv[i].y, w1.w, acc[i].w);
            acc[i].x = fmaf(xv[i].z, w2.x, acc[i].x); acc[i].y = fmaf(xv[i].z, w2.y, acc[i].y);
            acc[i].z = fmaf(xv[i].z, w2.z, acc[i].z); acc[i].w = fmaf(xv[i].z, w2.w, acc[i].w);
            acc[i].x = fmaf(xv[i].w, w3.x, acc[i].x); acc[i].y = fmaf(xv[i].w, w3.y, acc[i].y);
            acc[i].z = fmaf(xv[i].w, w3.z, acc[i].z); acc[i].w = fmaf(xv[i].w, w3.w, acc[i].w);
        }
    }

#pragma unroll
    for (int i = 0; i < 8; ++i) {
        int row = r0 + rg + 16 * i;
        if (row < N_NODES) {
            float s = dis[row];
            ushort4 s4 = make_ushort4(f2bf(acc[i].x * s), f2bf(acc[i].y * s),
                                      f2bf(acc[i].z * s), f2bf(acc[i].w * s));
            *(ushort4*)&xw16[row * 64 + cg * 4] = s4;
        }
    }
}

// ---------- gather: one wave per node, unroll-8, bf16 rows ----------
__global__ __launch_bounds__(256) void k_gather(const int* __restrict__ start,
                                                const int2* __restrict__ rec,
                                                const unsigned short* __restrict__ xw16,
                                                const float* __restrict__ dis,
                                                const float* __restrict__ bias,
                                                float* __restrict__ out) {
    int wave = threadIdx.x >> 6;
    int c = threadIdx.x & 63;
    int n = blockIdx.x * 4 + wave;   // 12500 * 4 = 50000 exact
    float di = dis[n];
    float acc0 = bf2f(xw16[n * 64 + c]);   // self-loop (xw pre-scaled by dis)
    float acc1 = 0.f, acc2 = 0.f, acc3 = 0.f, acc4 = 0.f, acc5 = 0.f, acc6 = 0.f, acc7 = 0.f;
    int j = start[n], jend = start[n + 1];   // multiple of 8 (zero-padded)
    for (; j < jend; j += 8) {
        int2 r0 = rec[j + 0], r1 = rec[j + 1], r2 = rec[j + 2], r3 = rec[j + 3];
        int2 r4 = rec[j + 4], r5 = rec[j + 5], r6 = rec[j + 6], r7 = rec[j + 7];
        float v0 = bf2f(xw16[r0.x * 64 + c]), v1 = bf2f(xw16[r1.x * 64 + c]);
        float v2 = bf2f(xw16[r2.x * 64 + c]), v3 = bf2f(xw16[r3.x * 64 + c]);
        float v4 = bf2f(xw16[r4.x * 64 + c]), v5 = bf2f(xw16[r5.x * 64 + c]);
        float v6 = bf2f(xw16[r6.x * 64 + c]), v7 = bf2f(xw16[r7.x * 64 + c]);
        acc0 = fmaf(v0, __int_as_float(r0.y), acc0);
        acc1 = fmaf(v1, __int_as_float(r1.y), acc1);
        acc2 = fmaf(v2, __int_as_float(r2.y), acc2);
        acc3 = fmaf(v3, __int_as_float(r3.y), acc3);
        acc4 = fmaf(v4, __int_as_float(r4.y), acc4);
        acc5 = fmaf(v5, __int_as_float(r5.y), acc5);
        acc6 = fmaf(v6, __int_as_float(r6.y), acc6);
        acc7 = fmaf(v7, __int_as_float(r7.y), acc7);
    }
    float acc = ((acc0 + acc1) + (acc2 + acc3)) + ((acc4 + acc5) + (acc6 + acc7));
    out[n * 64 + c] = fmaf(acc, di, bias[c]);
}

extern "C" void kernel_launch(void* const* d_in, const int* in_sizes, int n_in,
                              void* d_out, int out_size, void* d_ws, size_t ws_size,
                              hipStream_t stream) {
    const float* x    = (const float*)d_in[0];
    const float* W    = (const float*)d_in[1];
    const float* bias = (const float*)d_in[2];
    const float* ew   = (const float*)d_in[3];
    const int*   ei   = (const int*)d_in[4];   // (2,E) flat: [0:E) src, [E:2E) dst
    float* out = (float*)d_out;

    // ---- workspace layout (bytes) ----
    char* wsb = (char*)d_ws;
    int2*           rec   = (int2*)wsb;                        //  9,200,000 B
    unsigned short* xw16  = (unsigned short*)(wsb + 9200000);  //  6,400,000 B
    unsigned short* lrank = (unsigned short*)(wsb + 15600000); //  1,600,000 B
    unsigned short* part  = (unsigned short*)(wsb + 17200000); //  6,400,000 B
    float*          dis   = (float*)(wsb + 23600000);          //    200,000 B
    int*            cnttot= (int*)(wsb + 23800000);            //    200,000 B
    int*            start = (int*)(wsb + 24000000);            //    200,004 B
    int*            partials = (int*)(wsb + 24200016);

    const int NB_SCAN = (N_NODES + 1 + 511) / 512;   // 98
    const int NB_NODE = (N_NODES + 255) / 256;       // 196

    k_hist<<<NCHUNK * NRANGE, 256, 0, stream>>>(ei + N_EDGES, part, lrank);
    k_scanchunks<<<NB_NODE, 256, 0, stream>>>(part, cnttot);
    k_scan1<<<NB_SCAN, 256, 0, stream>>>(cnttot, start, partials);
    k_scan2<<<1, 128, 0, stream>>>(partials, NB_SCAN);
    k_scan3<<<NB_SCAN, 256, 0, stream>>>(start, partials);
    k_zero_rec<<<((REC_CAP * 8 / 16) + 255) / 256, 256, 0, stream>>>((float4*)rec);
    k_place<<<N_EDGES / 256, 256, 0, stream>>>(ei, ew, start, part, lrank, rec);
    k_deg<<<NB_NODE, 256, 0, stream>>>(start, rec, dis);
    k_xw<<<(N_NODES + 127) / 128, 256, 0, stream>>>(x, W, dis, xw16);
    k_gather<<<N_NODES / 4, 256, 0, stream>>>(start, rec, xw16, dis, bias, out);
}

// Round 8
// 105.710 us; speedup vs baseline: 2.4041x; 1.0326x over previous
//
#include <hip/hip_runtime.h>

#define N_NODES 50000
#define N_EDGES 800000
#define D 64
#define NCHUNK 64
#define CHUNK_E (N_EDGES / NCHUNK)   // 12500 edges per chunk
#define NRANGE 8
#define RANGE_N 8192                 // nodes per range (pow2); 8*8192 >= 50000
#define PAD 8                        // bucket padding -> pure unroll-8 gather
#define REC_CAP (N_EDGES + (PAD - 1) * N_NODES)   // 1,150,000 records max
#define REC_F4 ((REC_CAP * 8) / 16)               // 575,000 float4s
#define NB_NODE 196                               // ceil(50001/256)
#define ZERO_BLOCKS ((REC_F4 + 255) / 256)        // 2247

__device__ __forceinline__ unsigned short f2bf(float f) {   // RNE float->bf16
    unsigned int u = __float_as_uint(f);
    u += 0x7FFFu + ((u >> 16) & 1u);
    return (unsigned short)(u >> 16);
}
__device__ __forceinline__ float bf2f(unsigned short s) {
    return __uint_as_float((unsigned int)s << 16);
}

// ---------- LDS histogram + local ranks (no global atomics) ----------
__global__ __launch_bounds__(256) void k_hist(const int* __restrict__ col,
                                              unsigned short* __restrict__ part,
                                              unsigned short* __restrict__ lrank) {
    __shared__ unsigned int h[RANGE_N];   // 32 KiB
    int i = blockIdx.x >> 3;   // chunk 0..63
    int j = blockIdx.x & 7;    // range 0..7
    int t = threadIdx.x;
    for (int k = t; k < RANGE_N; k += 256) h[k] = 0;
    __syncthreads();
    int base = i * CHUNK_E;
    for (int e = base + t; e < base + CHUNK_E; e += 256) {
        int c = col[e];
        if ((c >> 13) == j) {
            unsigned int lr = atomicAdd(&h[c & (RANGE_N - 1)], 1u);
            lrank[e] = (unsigned short)lr;
        }
    }
    __syncthreads();
    for (int k = t; k < RANGE_N; k += 256) {
        int n = j * RANGE_N + k;
        if (n < N_NODES) part[(size_t)i * N_NODES + n] = (unsigned short)h[k];
    }
}

// ---------- fused: per-node chunk scan + block-local node scan + zero rec ----------
// path A (196 blocks): convert part to within-chunk exclusive prefixes, compute
//   padded bucket size, LDS-scan 256 nodes, write block-local start + block total.
// path B (2247 blocks): zero the rec buffer (pads must be (0, 0.0f)).
__global__ __launch_bounds__(256) void k_scanzero(unsigned short* __restrict__ part,
                                                  int* __restrict__ start,
                                                  int* __restrict__ partials,
                                                  float4* __restrict__ rec4) {
    int b = blockIdx.x, t = threadIdx.x;
    if (b < NB_NODE) {
        __shared__ int s[256];
        int n = b * 256 + t;
        unsigned int run = 0;
        if (n < N_NODES) {
#pragma unroll 8
            for (int i = 0; i < NCHUNK; ++i) {
                size_t idx = (size_t)i * N_NODES + n;
                unsigned int v = part[idx];
                part[idx] = (unsigned short)run;
                run += v;
            }
        }
        int cnt = (n < N_NODES) ? (int)((run + PAD - 1) & ~(unsigned)(PAD - 1)) : 0;
        s[t] = cnt;
        __syncthreads();
        for (int off = 1; off < 256; off <<= 1) {
            int a = (t >= off) ? s[t - off] : 0;
            __syncthreads();
            s[t] += a;
            __syncthreads();
        }
        if (n <= N_NODES) start[n] = s[t] - cnt;   // block-local exclusive prefix
        if (t == 255) partials[b] = s[255];        // block total
    } else {
        int idx = (b - NB_NODE) * 256 + t;
        if (idx < REC_F4) rec4[idx] = make_float4(0.f, 0.f, 0.f, 0.f);
    }
}

// ---------- finalize start: each block redundantly reduces its partials prefix ----------
__global__ __launch_bounds__(256) void k_scanfin(int* __restrict__ start,
                                                 const int* __restrict__ partials) {
    __shared__ int red[256];
    int b = blockIdx.x, t = threadIdx.x;
    red[t] = (t < b) ? partials[t] : 0;   // b <= 195 < 256
    __syncthreads();
    for (int off = 128; off > 0; off >>= 1) {
        if (t < off) red[t] += red[t + off];
        __syncthreads();
    }
    int offset = red[0];
    int n = b * 256 + t;
    if (n <= N_NODES) start[n] += offset;
}

// ---------- place records (src, ew) at deterministic positions ----------
__global__ __launch_bounds__(256) void k_place(const int* __restrict__ ei,
                                               const float* __restrict__ ew,
                                               const int* __restrict__ start,
                                               const unsigned short* __restrict__ part,
                                               const unsigned short* __restrict__ lrank,
                                               int2* __restrict__ rec) {
    int e = blockIdx.x * blockDim.x + threadIdx.x;
    if (e < N_EDGES) {
        int c = ei[N_EDGES + e];
        int i = e / CHUNK_E;
        int pos = start[c] + (int)part[(size_t)i * N_NODES + c] + (int)lrank[e];
        rec[pos] = make_int2(ei[e], __float_as_int(ew[e]));
    }
}

// ---------- deg from CSR, wave-parallel: one wave per node ----------
__global__ __launch_bounds__(256) void k_deg(const int* __restrict__ start,
                                             const int2* __restrict__ rec,
                                             float* __restrict__ dis) {
    int wave = threadIdx.x >> 6;
    int lane = threadIdx.x & 63;
    int n = blockIdx.x * 4 + wave;   // 12500 * 4 = 50000 exact
    int j0 = start[n], j1 = start[n + 1];
    float s = 0.0f;
    for (int j = j0 + lane; j < j1; j += 64) s += __int_as_float(rec[j].y);  // pads add 0
    for (int off = 32; off > 0; off >>= 1) s += __shfl_down(s, off);
    if (lane == 0) dis[n] = rsqrtf(1.0f + s);   // self-loop weight 1
}

// ---------- xw16 = bf16( dis[row] * (x @ W) )  (pre-scaled rows) ----------
__global__ __launch_bounds__(256) void k_xw(const float* __restrict__ x,
                                            const float* __restrict__ W,
                                            const float* __restrict__ dis,
                                            unsigned short* __restrict__ xw16) {
    __shared__ float Ws[64 * 64];
    __shared__ float xs[128 * 68];
    int t = threadIdx.x;
    int r0 = blockIdx.x * 128;

    for (int i = t; i < 1024; i += 256)
        ((float4*)Ws)[i] = ((const float4*)W)[i];
    for (int i = t; i < 2048; i += 256) {
        int row = i >> 4, k4 = i & 15;
        int gr = r0 + row;
        float4 v = make_float4(0.f, 0.f, 0.f, 0.f);
        if (gr < N_NODES) v = ((const float4*)x)[gr * 16 + k4];
        *(float4*)&xs[row * 68 + k4 * 4] = v;
    }
    __syncthreads();

    int cg = t & 15;
    int rg = t >> 4;
    float4 acc[8];
#pragma unroll
    for (int i = 0; i < 8; ++i) acc[i] = make_float4(0.f, 0.f, 0.f, 0.f);

    for (int k4 = 0; k4 < 16; ++k4) {
        float4 xv[8];
#pragma unroll
        for (int i = 0; i < 8; ++i)
            xv[i] = *(const float4*)&xs[(rg + 16 * i) * 68 + k4 * 4];
        float4 w0 = *(const float4*)&Ws[(k4 * 4 + 0) * 64 + cg * 4];
        float4 w1 = *(const float4*)&Ws[(k4 * 4 + 1) * 64 + cg * 4];
        float4 w2 = *(const float4*)&Ws[(k4 * 4 + 2) * 64 + cg * 4];
        float4 w3 = *(const float4*)&Ws[(k4 * 4 + 3) * 64 + cg * 4];
#pragma unroll
        for (int i = 0; i < 8; ++i) {
            acc[i].x = fmaf(xv[i].x, w0.x, acc[i].x); acc[i].y = fmaf(xv[i].x, w0.y, acc[i].y);
            acc[i].z = fmaf(xv[i].x, w0.z, acc[i].z); acc[i].w = fmaf(xv[i].x, w0.w, acc[i].w);
            acc[i].x = fmaf(xv[i].y, w1.x, acc[i].x); acc[i].y = fmaf(xv[i].y, w1.y, acc[i].y);
            acc[i].z = fmaf(xv[i].y, w1.z, acc[i].z); acc[i].w = fmaf(xv[i].y, w1.w, acc[i].w);
            acc[i].x = fmaf(xv[i].z, w2.x, acc[i].x); acc[i].y = fmaf(xv[i].z, w2.y, acc[i].y);
            acc[i].z = fmaf(xv[i].z, w2.z, acc[i].z); acc[i].w = fmaf(xv[i].z, w2.w, acc[i].w);
            acc[i].x = fmaf(xv[i].w, w3.x, acc[i].x); acc[i].y = fmaf(xv[i].w, w3.y, acc[i].y);
            acc[i].z = fmaf(xv[i].w, w3.z, acc[i].z); acc[i].w = fmaf(xv[i].w, w3.w, acc[i].w);
        }
    }

#pragma unroll
    for (int i = 0; i < 8; ++i) {
        int row = r0 + rg + 16 * i;
        if (row < N_NODES) {
            float s = dis[row];
            ushort4 s4 = make_ushort4(f2bf(acc[i].x * s), f2bf(acc[i].y * s),
                                      f2bf(acc[i].z * s), f2bf(acc[i].w * s));
            *(ushort4*)&xw16[row * 64 + cg * 4] = s4;
        }
    }
}

// ---------- gather: one wave per node, unroll-8, bf16 rows, int4 rec loads ----------
__global__ __launch_bounds__(256) void k_gather(const int* __restrict__ start,
                                                const int2* __restrict__ rec,
                                                const unsigned short* __restrict__ xw16,
                                                const float* __restrict__ dis,
                                                const float* __restrict__ bias,
                                                float* __restrict__ out) {
    int wave = threadIdx.x >> 6;
    int c = threadIdx.x & 63;
    int n = blockIdx.x * 4 + wave;   // 12500 * 4 = 50000 exact
    float di = dis[n];
    float acc0 = bf2f(xw16[n * 64 + c]);   // self-loop (xw pre-scaled by dis)
    float acc1 = 0.f, acc2 = 0.f, acc3 = 0.f, acc4 = 0.f, acc5 = 0.f, acc6 = 0.f, acc7 = 0.f;
    int j = start[n], jend = start[n + 1];          // multiples of 8 -> 64B aligned
    const int4* rq = (const int4*)(rec + j);        // 4 records per int4-pair; 4 int4 per 8
    for (; j < jend; j += 8, rq += 4) {
        int4 q0 = rq[0], q1 = rq[1], q2 = rq[2], q3 = rq[3];
        float v0 = bf2f(xw16[q0.x * 64 + c]), v1 = bf2f(xw16[q0.z * 64 + c]);
        float v2 = bf2f(xw16[q1.x * 64 + c]), v3 = bf2f(xw16[q1.z * 64 + c]);
        float v4 = bf2f(xw16[q2.x * 64 + c]), v5 = bf2f(xw16[q2.z * 64 + c]);
        float v6 = bf2f(xw16[q3.x * 64 + c]), v7 = bf2f(xw16[q3.z * 64 + c]);
        acc0 = fmaf(v0, __int_as_float(q0.y), acc0);
        acc1 = fmaf(v1, __int_as_float(q0.w), acc1);
        acc2 = fmaf(v2, __int_as_float(q1.y), acc2);
        acc3 = fmaf(v3, __int_as_float(q1.w), acc3);
        acc4 = fmaf(v4, __int_as_float(q2.y), acc4);
        acc5 = fmaf(v5, __int_as_float(q2.w), acc5);
        acc6 = fmaf(v6, __int_as_float(q3.y), acc6);
        acc7 = fmaf(v7, __int_as_float(q3.w), acc7);
    }
    float acc = ((acc0 + acc1) + (acc2 + acc3)) + ((acc4 + acc5) + (acc6 + acc7));
    out[n * 64 + c] = fmaf(acc, di, bias[c]);
}

extern "C" void kernel_launch(void* const* d_in, const int* in_sizes, int n_in,
                              void* d_out, int out_size, void* d_ws, size_t ws_size,
                              hipStream_t stream) {
    const float* x    = (const float*)d_in[0];
    const float* W    = (const float*)d_in[1];
    const float* bias = (const float*)d_in[2];
    const float* ew   = (const float*)d_in[3];
    const int*   ei   = (const int*)d_in[4];   // (2,E) flat: [0:E) src, [E:2E) dst
    float* out = (float*)d_out;

    // ---- workspace layout (bytes) ----
    char* wsb = (char*)d_ws;
    int2*           rec   = (int2*)wsb;                        //  9,200,000 B
    unsigned short* xw16  = (unsigned short*)(wsb + 9200000);  //  6,400,000 B
    unsigned short* lrank = (unsigned short*)(wsb + 15600000); //  1,600,000 B
    unsigned short* part  = (unsigned short*)(wsb + 17200000); //  6,400,000 B
    float*          dis   = (float*)(wsb + 23600000);          //    200,000 B
    int*            start = (int*)(wsb + 24000000);            //    200,004 B
    int*            partials = (int*)(wsb + 24200016);         //        784 B

    k_hist<<<NCHUNK * NRANGE, 256, 0, stream>>>(ei + N_EDGES, part, lrank);
    k_scanzero<<<NB_NODE + ZERO_BLOCKS, 256, 0, stream>>>(part, start, partials, (float4*)rec);
    k_scanfin<<<NB_NODE, 256, 0, stream>>>(start, partials);
    k_place<<<N_EDGES / 256, 256, 0, stream>>>(ei, ew, start, part, lrank, rec);
    k_deg<<<N_NODES / 4, 256, 0, stream>>>(start, rec, dis);
    k_xw<<<(N_NODES + 127) / 128, 256, 0, stream>>>(x, W, dis, xw16);
    k_gather<<<N_NODES / 4, 256, 0, stream>>>(start, rec, xw16, dis, bias, out);
}

// Round 9
// 96.040 us; speedup vs baseline: 2.6461x; 1.1007x over previous
//
#include <hip/hip_runtime.h>

#define N_NODES 50000
#define N_EDGES 800000
#define D 64
#define NCHUNK 64
#define CHUNK_E (N_EDGES / NCHUNK)   // 12500 edges per chunk
#define NRANGE 4
#define RANGE_N 16384                // nodes per range; packed u16 pairs in 32KB LDS
#define PAD 16                       // bucket padding -> pure unroll-16 gather
#define REC_CAP (N_EDGES + (PAD - 1) * N_NODES)   // 1,550,000 records max
#define NB_NODE 196                               // ceil(50001/256)
#define PLACE_BLOCKS (N_EDGES / 256)              // 3125

__device__ __forceinline__ unsigned short f2bf(float f) {   // RNE float->bf16
    unsigned int u = __float_as_uint(f);
    u += 0x7FFFu + ((u >> 16) & 1u);
    return (unsigned short)(u >> 16);
}
__device__ __forceinline__ float bf2f(unsigned short s) {
    return __uint_as_float((unsigned int)s << 16);
}

// ---------- packed-u16 LDS histogram + local ranks ----------
// 2 nodes per u32 word; counts < 12500 so halves never carry.
__global__ __launch_bounds__(1024) void k_hist(const int* __restrict__ col,
                                               unsigned short* __restrict__ part,
                                               unsigned short* __restrict__ lrank) {
    __shared__ unsigned int h[RANGE_N / 2];   // 32 KiB
    int i = blockIdx.x >> 2;   // chunk 0..63
    int j = blockIdx.x & 3;    // range 0..3
    int t = threadIdx.x;
    for (int k = t; k < RANGE_N / 2; k += 1024) h[k] = 0;
    __syncthreads();
    int base = i * CHUNK_E;
    for (int e = base + t; e < base + CHUNK_E; e += 1024) {
        int c = col[e];
        if ((c >> 14) == j) {
            int local = c & (RANGE_N - 1);
            int sh = (local & 1) << 4;
            unsigned int lr = atomicAdd(&h[local >> 1], 1u << sh);
            lrank[e] = (unsigned short)((lr >> sh) & 0xffffu);
        }
    }
    __syncthreads();
    for (int k = t; k < RANGE_N; k += 1024) {
        int n = j * RANGE_N + k;
        if (n < N_NODES)
            part[(size_t)i * N_NODES + n] =
                (unsigned short)((h[k >> 1] >> ((k & 1) << 4)) & 0xffffu);
    }
}

// ---------- per-node chunk scan + block-local node scan (no zeroing) ----------
__global__ __launch_bounds__(256) void k_scan(unsigned short* __restrict__ part,
                                              int* __restrict__ start,
                                              int* __restrict__ cnttot,
                                              int* __restrict__ partials) {
    __shared__ int s[256];
    int b = blockIdx.x, t = threadIdx.x;
    int n = b * 256 + t;
    unsigned int run = 0;
    if (n < N_NODES) {
#pragma unroll 8
        for (int i = 0; i < NCHUNK; ++i) {
            size_t idx = (size_t)i * N_NODES + n;
            unsigned int v = part[idx];
            part[idx] = (unsigned short)run;
            run += v;
        }
        cnttot[n] = (int)run;   // unpadded count (for pad-fill)
    }
    int cnt = (n < N_NODES) ? (int)((run + PAD - 1) & ~(unsigned)(PAD - 1)) : 0;
    s[t] = cnt;
    __syncthreads();
    for (int off = 1; off < 256; off <<= 1) {
        int a = (t >= off) ? s[t - off] : 0;
        __syncthreads();
        s[t] += a;
        __syncthreads();
    }
    if (n <= N_NODES) start[n] = s[t] - cnt;   // block-local exclusive prefix
    if (t == 255) partials[b] = s[255];
}

// ---------- finalize start: each block reduces its partials prefix ----------
__global__ __launch_bounds__(256) void k_scanfin(int* __restrict__ start,
                                                 const int* __restrict__ partials) {
    __shared__ int red[256];
    int b = blockIdx.x, t = threadIdx.x;
    red[t] = (t < b) ? partials[t] : 0;   // b <= 195 < 256
    __syncthreads();
    for (int off = 128; off > 0; off >>= 1) {
        if (t < off) red[t] += red[t + off];
        __syncthreads();
    }
    int offset = red[0];
    int n = b * 256 + t;
    if (n <= N_NODES) start[n] += offset;
}

// ---------- place records + pad-fill bucket tails (fused, no LDS) ----------
__global__ __launch_bounds__(256) void k_place(const int* __restrict__ ei,
                                               const float* __restrict__ ew,
                                               const int* __restrict__ start,
                                               const int* __restrict__ cnttot,
                                               const unsigned short* __restrict__ part,
                                               const unsigned short* __restrict__ lrank,
                                               int2* __restrict__ rec) {
    int b = blockIdx.x, t = threadIdx.x;
    if (b < PLACE_BLOCKS) {
        int e = b * 256 + t;
        int c = ei[N_EDGES + e];
        int i = e / CHUNK_E;   // compile-time magic-div
        int pos = start[c] + (int)part[(size_t)i * N_NODES + c] + (int)lrank[e];
        rec[pos] = make_int2(ei[e], __float_as_int(ew[e]));
    } else {
        int n = (b - PLACE_BLOCKS) * 256 + t;
        if (n < N_NODES) {
            int j = start[n] + cnttot[n];
            int j1 = start[n + 1];
            for (; j < j1; ++j) rec[j] = make_int2(0, 0);   // (src=0, w=0.0f)
        }
    }
}

// ---------- deg from CSR, wave-parallel: one wave per node ----------
__global__ __launch_bounds__(256) void k_deg(const int* __restrict__ start,
                                             const int2* __restrict__ rec,
                                             float* __restrict__ dis) {
    int wave = threadIdx.x >> 6;
    int lane = threadIdx.x & 63;
    int n = blockIdx.x * 4 + wave;   // 12500 * 4 = 50000 exact
    int j0 = start[n], j1 = start[n + 1];
    float s = 0.0f;
    for (int j = j0 + lane; j < j1; j += 64) s += __int_as_float(rec[j].y);  // pads add 0
    for (int off = 32; off > 0; off >>= 1) s += __shfl_down(s, off);
    if (lane == 0) dis[n] = rsqrtf(1.0f + s);   // self-loop weight 1
}

// ---------- xw16 = bf16( dis[row] * (x @ W) ) ----------
__global__ __launch_bounds__(256) void k_xw(const float* __restrict__ x,
                                            const float* __restrict__ W,
                                            const float* __restrict__ dis,
                                            unsigned short* __restrict__ xw16) {
    __shared__ float Ws[64 * 64];
    __shared__ float xs[128 * 68];
    int t = threadIdx.x;
    int r0 = blockIdx.x * 128;

    for (int i = t; i < 1024; i += 256)
        ((float4*)Ws)[i] = ((const float4*)W)[i];
    for (int i = t; i < 2048; i += 256) {
        int row = i >> 4, k4 = i & 15;
        int gr = r0 + row;
        float4 v = make_float4(0.f, 0.f, 0.f, 0.f);
        if (gr < N_NODES) v = ((const float4*)x)[gr * 16 + k4];
        *(float4*)&xs[row * 68 + k4 * 4] = v;
    }
    __syncthreads();

    int cg = t & 15;
    int rg = t >> 4;
    float4 acc[8];
#pragma unroll
    for (int i = 0; i < 8; ++i) acc[i] = make_float4(0.f, 0.f, 0.f, 0.f);

    for (int k4 = 0; k4 < 16; ++k4) {
        float4 xv[8];
#pragma unroll
        for (int i = 0; i < 8; ++i)
            xv[i] = *(const float4*)&xs[(rg + 16 * i) * 68 + k4 * 4];
        float4 w0 = *(const float4*)&Ws[(k4 * 4 + 0) * 64 + cg * 4];
        float4 w1 = *(const float4*)&Ws[(k4 * 4 + 1) * 64 + cg * 4];
        float4 w2 = *(const float4*)&Ws[(k4 * 4 + 2) * 64 + cg * 4];
        float4 w3 = *(const float4*)&Ws[(k4 * 4 + 3) * 64 + cg * 4];
#pragma unroll
        for (int i = 0; i < 8; ++i) {
            acc[i].x = fmaf(xv[i].x, w0.x, acc[i].x); acc[i].y = fmaf(xv[i].x, w0.y, acc[i].y);
            acc[i].z = fmaf(xv[i].x, w0.z, acc[i].z); acc[i].w = fmaf(xv[i].x, w0.w, acc[i].w);
            acc[i].x = fmaf(xv[i].y, w1.x, acc[i].x); acc[i].y = fmaf(xv[i].y, w1.y, acc[i].y);
            acc[i].z = fmaf(xv[i].y, w1.z, acc[i].z); acc[i].w = fmaf(xv[i].y, w1.w, acc[i].w);
            acc[i].x = fmaf(xv[i].z, w2.x, acc[i].x); acc[i].y = fmaf(xv[i].z, w2.y, acc[i].y);
            acc[i].z = fmaf(xv[i].z, w2.z, acc[i].z); acc[i].w = fmaf(xv[i].z, w2.w, acc[i].w);
            acc[i].x = fmaf(xv[i].w, w3.x, acc[i].x); acc[i].y = fmaf(xv[i].w, w3.y, acc[i].y);
            acc[i].z = fmaf(xv[i].w, w3.z, acc[i].z); acc[i].w = fmaf(xv[i].w, w3.w, acc[i].w);
        }
    }

#pragma unroll
    for (int i = 0; i < 8; ++i) {
        int row = r0 + rg + 16 * i;
        if (row < N_NODES) {
            float s = dis[row];
            ushort4 s4 = make_ushort4(f2bf(acc[i].x * s), f2bf(acc[i].y * s),
                                      f2bf(acc[i].z * s), f2bf(acc[i].w * s));
            *(ushort4*)&xw16[row * 64 + cg * 4] = s4;
        }
    }
}

// ---------- gather: one wave per node, unroll-16, bf16 rows ----------
__global__ __launch_bounds__(256) void k_gather(const int* __restrict__ start,
                                                const int2* __restrict__ rec,
                                                const unsigned short* __restrict__ xw16,
                                                const float* __restrict__ dis,
                                                const float* __restrict__ bias,
                                                float* __restrict__ out) {
    int wave = threadIdx.x >> 6;
    int c = threadIdx.x & 63;
    int n = blockIdx.x * 4 + wave;   // 12500 * 4 = 50000 exact
    float di = dis[n];
    float acc[16];
#pragma unroll
    for (int k = 0; k < 16; ++k) acc[k] = 0.f;
    acc[0] = bf2f(xw16[n * 64 + c]);   // self-loop (xw pre-scaled by dis)
    int j = start[n], jend = start[n + 1];     // multiples of 16 -> 128B aligned
    const int4* rq = (const int4*)(rec + j);
    for (; j < jend; j += 16, rq += 8) {
        int4 q[8];
#pragma unroll
        for (int k = 0; k < 8; ++k) q[k] = rq[k];
        float v[16];
#pragma unroll
        for (int k = 0; k < 8; ++k) {
            v[2 * k]     = bf2f(xw16[q[k].x * 64 + c]);
            v[2 * k + 1] = bf2f(xw16[q[k].z * 64 + c]);
        }
#pragma unroll
        for (int k = 0; k < 8; ++k) {
            acc[2 * k]     = fmaf(v[2 * k],     __int_as_float(q[k].y), acc[2 * k]);
            acc[2 * k + 1] = fmaf(v[2 * k + 1], __int_as_float(q[k].w), acc[2 * k + 1]);
        }
    }
    float a = 0.f;
#pragma unroll
    for (int k = 0; k < 16; ++k) a += acc[k];
    out[n * 64 + c] = fmaf(a, di, bias[c]);
}

extern "C" void kernel_launch(void* const* d_in, const int* in_sizes, int n_in,
                              void* d_out, int out_size, void* d_ws, size_t ws_size,
                              hipStream_t stream) {
    const float* x    = (const float*)d_in[0];
    const float* W    = (const float*)d_in[1];
    const float* bias = (const float*)d_in[2];
    const float* ew   = (const float*)d_in[3];
    const int*   ei   = (const int*)d_in[4];   // (2,E) flat: [0:E) src, [E:2E) dst
    float* out = (float*)d_out;

    // ---- workspace layout (bytes) ----
    char* wsb = (char*)d_ws;
    int2*           rec   = (int2*)wsb;                         // 12,400,000 B
    unsigned short* xw16  = (unsigned short*)(wsb + 12400000);  //  6,400,000 B
    unsigned short* lrank = (unsigned short*)(wsb + 18800000);  //  1,600,000 B
    unsigned short* part  = (unsigned short*)(wsb + 20400000);  //  6,400,000 B
    float*          dis   = (float*)(wsb + 26800000);           //    200,000 B
    int*            cnttot= (int*)(wsb + 27000000);             //    200,000 B
    int*            start = (int*)(wsb + 27200000);             //    200,004 B
    int*            partials = (int*)(wsb + 27400016);          //        784 B

    k_hist<<<NCHUNK * NRANGE, 1024, 0, stream>>>(ei + N_EDGES, part, lrank);
    k_scan<<<NB_NODE, 256, 0, stream>>>(part, start, cnttot, partials);
    k_scanfin<<<NB_NODE, 256, 0, stream>>>(start, partials);
    k_place<<<PLACE_BLOCKS + NB_NODE, 256, 0, stream>>>(ei, ew, start, cnttot, part, lrank, rec);
    k_deg<<<N_NODES / 4, 256, 0, stream>>>(start, rec, dis);
    k_xw<<<(N_NODES + 127) / 128, 256, 0, stream>>>(x, W, dis, xw16);
    k_gather<<<N_NODES / 4, 256, 0, stream>>>(start, rec, xw16, dis, bias, out);
}